// Round 7
// baseline (471.110 us; speedup 1.0000x reference)
//
#include <hip/hip_runtime.h>

#define NN 50000      // nodes
#define NE 800000     // edges
#define ND 128        // node_attr_dim
#define ED 16         // edge_attr_dim
#define HID 300       // hidden
#define KP1 192       // padded K for gemm1 (128+16 -> 192)
#define KP2 320       // padded K for gemm2 (300 -> 320)
#define NP 320        // padded N (300 -> 320)

#define SCAN_T 256
#define SCAN_B ((NN + SCAN_T - 1) / SCAN_T)   // 196 blocks

typedef __attribute__((ext_vector_type(8))) short short8;
typedef __attribute__((ext_vector_type(4))) float f32x4;

__device__ __forceinline__ unsigned short f2b(float f) {
    unsigned int u = __float_as_uint(f);
    u = (u + 0x7FFFu + ((u >> 16) & 1u)) >> 16;   // RNE
    return (unsigned short)u;
}
__device__ __forceinline__ float blo(unsigned int u) {
    return __uint_as_float(u << 16);
}
__device__ __forceinline__ float bhi(unsigned int u) {
    return __uint_as_float(u & 0xffff0000u);
}

// async global->LDS: 16B per lane, dest = wave-uniform base + lane*16
__device__ __forceinline__ void gload16(const void* g, void* l) {
    __builtin_amdgcn_global_load_lds(
        (const __attribute__((address_space(1))) void*)g,
        (__attribute__((address_space(3))) void*)l, 16, 0, 0);
}

// in-block inclusive scan of v across 256 threads (4 waves)
__device__ __forceinline__ int block_iscan(int v, int tid) {
    int lane = tid & 63;
    #pragma unroll
    for (int off = 1; off < 64; off <<= 1) {
        int t = __shfl_up(v, off);
        if (lane >= off) v += t;
    }
    __shared__ int wsum[4];
    int wid = tid >> 6;
    if (lane == 63) wsum[wid] = v;
    __syncthreads();
    int add = 0;
    #pragma unroll
    for (int w = 0; w < 4; ++w)
        if (w < wid) add += wsum[w];
    return v + add;
}

// ---------------------------------------------------------------- CSR build
// 4 edges per thread (int4) -> 1/4 the wave count
__global__ void hist_kernel(const int* __restrict__ ei, int* __restrict__ rowptr) {
    int e4 = (blockIdx.x * blockDim.x + threadIdx.x) * 4;
    if (e4 < NE) {
        int4 d = *(const int4*)&ei[NE + e4];
        atomicAdd(&rowptr[d.x + 1], 1);
        atomicAdd(&rowptr[d.y + 1], 1);
        atomicAdd(&rowptr[d.z + 1], 1);
        atomicAdd(&rowptr[d.w + 1], 1);
    }
}

// phase 1: local inclusive scan of rowptr[1..NN], block totals out
__global__ __launch_bounds__(SCAN_T) void scan1(int* __restrict__ rowptr,
                                                int* __restrict__ blockSums) {
    int i = blockIdx.x * SCAN_T + threadIdx.x;
    int v = (i < NN) ? rowptr[1 + i] : 0;
    v = block_iscan(v, threadIdx.x);
    if (i < NN) rowptr[1 + i] = v;
    if (threadIdx.x == SCAN_T - 1) blockSums[blockIdx.x] = v;
}

// phase 2: exclusive scan of block totals (196 <= 256, one block)
__global__ __launch_bounds__(SCAN_T) void scan2(int* __restrict__ blockSums) {
    int t = threadIdx.x;
    int orig = (t < SCAN_B) ? blockSums[t] : 0;
    int v = block_iscan(orig, t);
    if (t < SCAN_B) blockSums[t] = v - orig;   // exclusive
}

// phase 3: add block offsets; emit cursor[] (exclusive prefix per node)
__global__ __launch_bounds__(SCAN_T) void scan3(int* __restrict__ rowptr,
                                                const int* __restrict__ blockSums,
                                                int* __restrict__ cursor) {
    int i = blockIdx.x * SCAN_T + threadIdx.x;
    if (i < NN) {
        int v = rowptr[1 + i] + blockSums[blockIdx.x];
        rowptr[1 + i] = v;
        if (i + 1 < NN) cursor[i + 1] = v;
    }
    if (i == 0) cursor[0] = 0;
}

// single packed CSR payload: csr[pos] = {src, eid, w_bits, 0}
__global__ void fill_kernel(const int* __restrict__ ei, const float* __restrict__ ew,
                            int* __restrict__ cursor, uint4* __restrict__ csr) {
    int e = blockIdx.x * blockDim.x + threadIdx.x;
    if (e < NE) {
        int d = ei[NE + e];
        int pos = atomicAdd(&cursor[d], 1);
        uint4 q;
        q.x = (unsigned int)ei[e];
        q.y = (unsigned int)e;
        q.z = __float_as_uint(ew[e]);
        q.w = 0;
        csr[pos] = q;
    }
}

// ---- prep: fused cast_x + inc. Wave per node; inc gather 4-deep per group.
__global__ __launch_bounds__(256) void prep_kernel(
    const float* __restrict__ x,
    const float* __restrict__ edge_attr,
    const int* __restrict__ rowptr,
    const uint4* __restrict__ csr,
    unsigned short* __restrict__ A1) {
    int n = (blockIdx.x * blockDim.x + threadIdx.x) >> 6;
    int lane = threadIdx.x & 63;
    if (n >= NN) return;

    float2 v = *(const float2*)&x[(size_t)n * ND + lane * 2];
    unsigned int o = (unsigned int)f2b(v.x) | ((unsigned int)f2b(v.y) << 16);
    *(unsigned int*)&A1[(size_t)n * KP1 + lane * 2] = o;

    int g = lane >> 4, j = lane & 15;
    int lo = rowptr[n], hi = rowptr[n + 1];
    float s = 0.f;
    for (int k = lo + g; k < hi; k += 16) {       // 4 edges per group in flight
        int k1 = (k + 4  < hi) ? k + 4  : k;
        int k2 = (k + 8  < hi) ? k + 8  : k;
        int k3 = (k + 12 < hi) ? k + 12 : k;
        uint4 e0 = csr[k],  e1 = csr[k1];
        uint4 e2 = csr[k2], e3 = csr[k3];
        float a0 = edge_attr[(size_t)e0.y * ED + j];
        float a1 = edge_attr[(size_t)e1.y * ED + j];
        float a2 = edge_attr[(size_t)e2.y * ED + j];
        float a3 = edge_attr[(size_t)e3.y * ED + j];
        s += __uint_as_float(e0.z) * a0;
        s += ((k + 4  < hi) ? __uint_as_float(e1.z) : 0.f) * a1;
        s += ((k + 8  < hi) ? __uint_as_float(e2.z) : 0.f) * a2;
        s += ((k + 12 < hi) ? __uint_as_float(e3.z) : 0.f) * a3;
    }
    s += __shfl_xor(s, 16);
    s += __shfl_xor(s, 32);
    if (lane < 16)
        A1[(size_t)n * KP1 + ND + lane] = f2b(s);
    else
        A1[(size_t)n * KP1 + ND + lane] = 0;      // pad cols 144..191
}

// B0T[n][k] = bf16(W0[k][n]) padded to [320][192]
__global__ void castB0(const float* __restrict__ W0, unsigned short* __restrict__ B0T) {
    int n = blockIdx.x, k = threadIdx.x;
    float v = (n < HID && k < ND + ED) ? W0[(size_t)k * HID + n] : 0.f;
    B0T[(size_t)n * KP1 + k] = f2b(v);
}

// BT[n][k] = bf16(W[k][n]) padded to [320][320]
__global__ void castB(const float* __restrict__ W, unsigned short* __restrict__ BT) {
    int n = blockIdx.x, k = threadIdx.x;
    float v = (n < HID && k < HID) ? W[(size_t)k * HID + n] : 0.f;
    BT[(size_t)n * KP2 + k] = f2b(v);
}

// --------------------------------------------- persistent stream-M MFMA GEMM
// 512 threads (8 waves = 2/SIMD), 1 block/CU. B panel LDS-resident (staged
// once, XOR-swizzled, rule 21). A fragments loaded DIRECTLY global->VGPR
// (A is single-use per wave -- LDS staging bought nothing; round-3's failure
// was direct-loading B, the reused operand). Main loop has ZERO barriers:
// latency hidden by unrolled-tt ILP x 2-waves/SIMD TLP.
template <int MODE, int KP, int BN, int WM, int WN, int RPB, int TM>
__global__ __launch_bounds__(512) void gemm_stream(
    const unsigned short* __restrict__ A,   // [M, KP] bf16 row-major
    const unsigned short* __restrict__ BT,  // [320, KP] bf16 (B transposed)
    const float* __restrict__ bias,         // [300]
    const float* __restrict__ RES,          // MODE1: h0 [M,300] fp32
    float* __restrict__ C,                  // [M,300] fp32
    unsigned short* __restrict__ h0b,       // MODE0: [M,320] bf16
    int M)
{
    constexpr int CPR = KP / 8;           // 16B chunks per row
    constexpr int BCH = BN * CPR;         // chunks in B panel
    constexpr int BNW = BN / (16 * WN);   // b-frags per wave (=5)
    __shared__ unsigned short Bs[BN * KP];   // g1:120KB g2:100KB

    const int tid = threadIdx.x;
    const int wave = tid >> 6, lane = tid & 63;
    const int wm = wave / WN, wn = wave % WN;
    const int quad = lane >> 4, lr = lane & 15;
    const int n00 = blockIdx.y * BN;
    const int ncol = n00 + wn * (BNW * 16);
    const int rbase = blockIdx.x * RPB;
    const int rowend = min(rbase + RPB, M);
    const int nt = (rowend - rbase + TM - 1) / TM;

    // ---- stage B panel once (swizzled source, linear dest); BCH % 512 may
    // be nonzero but BCH % 64 == 0, so the guard cuts at wave granularity.
    for (int s = tid; s < BCH; s += 512) {
        int row = s / CPR, c = s - row * CPR;
        int cs = (c & ~7) | ((c & 7) ^ (row & 7));
        gload16(&BT[(size_t)(n00 + row) * KP + cs * 8], &Bs[s * 8]);
    }
    float bias_r[BNW];
    #pragma unroll
    for (int tn = 0; tn < BNW; ++tn) {
        int ng = ncol + tn * 16 + lr;
        bias_r[tn] = (ng < HID) ? bias[ng] : 0.f;
    }
    __syncthreads();   // only barrier: B panel resident

    #pragma unroll 1
    for (int t = 0; t < nt; ++t) {
        const int mb = rbase + t * TM;
        int arow = mb + wm * 16 + lr; if (arow >= M) arow = M - 1;
        const unsigned short* ap = A + (size_t)arow * KP;

        float res_r[BNW][4];
        if (MODE == 1) {   // residual prefetch; drains at epilogue use
            #pragma unroll
            for (int tn = 0; tn < BNW; ++tn) {
                int ng = ncol + tn * 16 + lr;
                int ngc = ng < HID ? ng : HID - 1;
                #pragma unroll
                for (int r = 0; r < 4; ++r) {
                    int mg = mb + wm * 16 + quad * 4 + r;
                    int mgc = mg < M ? mg : M - 1;
                    res_r[tn][r] = RES[(size_t)mgc * HID + ngc];
                }
            }
        }

        f32x4 acc[BNW] = {};
        const int rm = lr & 7;
        #pragma unroll
        for (int tt = 0; tt < KP / 32; ++tt) {
            short8 a = *(const short8*)&ap[tt * 32 + quad * 8];
            int cB = tt * 4 + quad;
            int sw8 = ((cB & ~7) | ((cB & 7) ^ rm)) * 8;
            short8 b[BNW];
            #pragma unroll
            for (int tn = 0; tn < BNW; ++tn)
                b[tn] = *(const short8*)&Bs[(wn * (BNW * 16) + tn * 16 + lr) * KP + sw8];
            #pragma unroll
            for (int tn = 0; tn < BNW; ++tn)
                acc[tn] = __builtin_amdgcn_mfma_f32_16x16x32_bf16(
                    a, b[tn], acc[tn], 0, 0, 0);
        }

        #pragma unroll
        for (int tn = 0; tn < BNW; ++tn) {
            int ng = ncol + tn * 16 + lr;
            #pragma unroll
            for (int r = 0; r < 4; ++r) {
                int mg = mb + wm * 16 + quad * 4 + r;
                if (mg < rowend && ng < HID) {
                    float v = acc[tn][r] + bias_r[tn];
                    if (MODE == 1) v += res_r[tn][r];
                    v = fmaxf(v, 0.f);
                    C[(size_t)mg * HID + ng] = v;
                    if (MODE == 0) h0b[(size_t)mg * NP + ng] = f2b(v);
                }
            }
        }
    }
}

// ---------------- aggB[n] = bf16(mean_k w_k * h0b[src_k]) ------------------
__device__ __forceinline__ void acc8(float* acc, float w, const uint4& r) {
    acc[0] += w * blo(r.x); acc[1] += w * bhi(r.x);
    acc[2] += w * blo(r.y); acc[3] += w * bhi(r.y);
    acc[4] += w * blo(r.z); acc[5] += w * bhi(r.z);
    acc[6] += w * blo(r.w); acc[7] += w * bhi(r.w);
}

// wave per node; 40 lanes x 16B cover the 640B row; FOUR gathered rows in
// flight, clamped-index predication removes the serial tail entirely.
__global__ __launch_bounds__(256) void agg_kernel(
    const unsigned short* __restrict__ h0b,   // [NN, 320] bf16
    const int* __restrict__ rowptr,
    const uint4* __restrict__ csr,
    unsigned short* __restrict__ aggB)        // [NN, 320] bf16, pad cols = 0
{
    int n = (blockIdx.x * blockDim.x + threadIdx.x) >> 6;
    int lane = threadIdx.x & 63;
    if (n >= NN) return;
    int lo = rowptr[n], hi = rowptr[n + 1];
    float acc[8] = {};
    const uint4* h4 = (const uint4*)h0b;      // row stride = 40 uint4
    bool act = lane < 40;
    for (int k = lo; k < hi; k += 4) {        // 4-deep, clamp-predicated
        int k1 = (k + 1 < hi) ? k + 1 : k;
        int k2 = (k + 2 < hi) ? k + 2 : k;
        int k3 = (k + 3 < hi) ? k + 3 : k;
        uint4 p0 = csr[k], p1 = csr[k1], p2 = csr[k2], p3 = csr[k3];
        float w0 = __uint_as_float(p0.z);
        float w1 = (k + 1 < hi) ? __uint_as_float(p1.z) : 0.f;
        float w2 = (k + 2 < hi) ? __uint_as_float(p2.z) : 0.f;
        float w3 = (k + 3 < hi) ? __uint_as_float(p3.z) : 0.f;
        uint4 r0 = {0,0,0,0}, r1 = {0,0,0,0}, r2 = {0,0,0,0}, r3 = {0,0,0,0};
        if (act) {
            r0 = h4[(size_t)p0.x * 40 + lane];
            r1 = h4[(size_t)p1.x * 40 + lane];
            r2 = h4[(size_t)p2.x * 40 + lane];
            r3 = h4[(size_t)p3.x * 40 + lane];
        }
        acc8(acc, w0, r0);
        acc8(acc, w1, r1);
        acc8(acc, w2, r2);
        acc8(acc, w3, r3);
    }
    if (act) {
        float invd = 1.f / fmaxf((float)(hi - lo), 1.f);
        int cbase = lane * 8;
        unsigned int o[4];
        #pragma unroll
        for (int i = 0; i < 4; ++i) {
            int c0 = cbase + 2 * i, c1 = c0 + 1;
            unsigned int ulo = (c0 < HID) ? f2b(acc[2 * i] * invd) : 0;
            unsigned int uhi = (c1 < HID) ? f2b(acc[2 * i + 1] * invd) : 0;
            o[i] = ulo | (uhi << 16);
        }
        uint4* a4 = (uint4*)aggB;
        uint4 v; v.x = o[0]; v.y = o[1]; v.z = o[2]; v.w = o[3];
        a4[(size_t)n * 40 + lane] = v;
    }
}

// ---------------------------------------------------------------- launch
extern "C" void kernel_launch(void* const* d_in, const int* in_sizes, int n_in,
                              void* d_out, int out_size, void* d_ws, size_t ws_size,
                              hipStream_t stream) {
    const float* x           = (const float*)d_in[0];
    const float* edge_attr   = (const float*)d_in[1];
    const float* edge_weight = (const float*)d_in[2];
    const float* W0 = (const float*)d_in[4];
    const float* b0 = (const float*)d_in[5];
    const float* W  = (const float*)d_in[6];
    const float* b  = (const float*)d_in[7];
    const int* ei   = (const int*)d_in[8];

    float* out = (float*)d_out;
    float* h  = out;                          // output 0: [NN, HID]
    float* h0 = out + (size_t)NN * HID;       // output 1: [NN, HID]

    char* p = (char*)d_ws;
    auto alloc = [&](size_t bytes) { char* q = p; p += (bytes + 255) & ~(size_t)255; return q; };
    int*   rowptr  = (int*)  alloc((NN + 1) * sizeof(int));
    int*   cursor  = (int*)  alloc(NN * sizeof(int));
    int*   bsums   = (int*)  alloc(SCAN_B * sizeof(int));
    uint4* csr     = (uint4*)alloc((size_t)NE * sizeof(uint4));
    unsigned short* A1   = (unsigned short*)alloc((size_t)NN * KP1 * 2);
    unsigned short* h0b  = (unsigned short*)alloc((size_t)NN * NP * 2);
    unsigned short* aggB = (unsigned short*)alloc((size_t)NN * NP * 2);
    unsigned short* B0T  = (unsigned short*)alloc((size_t)NP * KP1 * 2);
    unsigned short* BT   = (unsigned short*)alloc((size_t)NP * KP2 * 2);

    hipMemsetAsync(rowptr, 0, (NN + 1) * sizeof(int), stream);
    hist_kernel<<<(NE / 4 + 255) / 256, 256, 0, stream>>>(ei, rowptr);
    scan1<<<SCAN_B, SCAN_T, 0, stream>>>(rowptr, bsums);
    scan2<<<1, SCAN_T, 0, stream>>>(bsums);
    scan3<<<SCAN_B, SCAN_T, 0, stream>>>(rowptr, bsums, cursor);
    fill_kernel<<<(NE + 255) / 256, 256, 0, stream>>>(ei, edge_weight, cursor, csr);
    castB0<<<NP, KP1, 0, stream>>>(W0, B0T);
    castB<<<NP, KP2, 0, stream>>>(W, BT);
    prep_kernel<<<(NN + 3) / 4, 256, 0, stream>>>(x, edge_attr, rowptr, csr, A1);

    // gemm1: 256 blocks (1/CU), 8 waves, full N=320 panel, 32-row tiles
    gemm_stream<0, KP1, 320, 2, 4, 196, 32><<<dim3(256, 1), 512, 0, stream>>>(
        A1, B0T, b0, nullptr, h0, h0b, NN);
    agg_kernel<<<(NN + 3) / 4, 256, 0, stream>>>(h0b, rowptr, csr, aggB);
    // gemm2: 128x2 blocks (1/CU), 8 waves, N-half=160 panel, 64-row tiles
    gemm_stream<1, KP2, 160, 4, 2, 391, 64><<<dim3(128, 2), 512, 0, stream>>>(
        aggB, BT, b, h0, h, nullptr, NN);
}

// Round 9
// 457.720 us; speedup vs baseline: 1.0293x; 1.0293x over previous
//
#include <hip/hip_runtime.h>

#define NN 50000      // nodes
#define NE 800000     // edges
#define ND 128        // node_attr_dim
#define ED 16         // edge_attr_dim
#define HID 300       // hidden
#define KP1 192       // padded K for gemm1 (128+16 -> 192)
#define KP2 320       // padded K for gemm2 (300 -> 320)
#define NP 320        // padded N (300 -> 320)

#define SCAN_T 256
#define SCAN_B ((NN + SCAN_T - 1) / SCAN_T)   // 196 blocks

typedef __attribute__((ext_vector_type(8))) short short8;
typedef __attribute__((ext_vector_type(4))) float f32x4;

__device__ __forceinline__ unsigned short f2b(float f) {
    unsigned int u = __float_as_uint(f);
    u = (u + 0x7FFFu + ((u >> 16) & 1u)) >> 16;   // RNE
    return (unsigned short)u;
}
__device__ __forceinline__ float blo(unsigned int u) {
    return __uint_as_float(u << 16);
}
__device__ __forceinline__ float bhi(unsigned int u) {
    return __uint_as_float(u & 0xffff0000u);
}

// async global->LDS: 16B per lane, dest = wave-uniform base + lane*16
__device__ __forceinline__ void gload16(const void* g, void* l) {
    __builtin_amdgcn_global_load_lds(
        (const __attribute__((address_space(1))) void*)g,
        (__attribute__((address_space(3))) void*)l, 16, 0, 0);
}

// in-block inclusive scan of v across 256 threads (4 waves)
__device__ __forceinline__ int block_iscan(int v, int tid) {
    int lane = tid & 63;
    #pragma unroll
    for (int off = 1; off < 64; off <<= 1) {
        int t = __shfl_up(v, off);
        if (lane >= off) v += t;
    }
    __shared__ int wsum[4];
    int wid = tid >> 6;
    if (lane == 63) wsum[wid] = v;
    __syncthreads();
    int add = 0;
    #pragma unroll
    for (int w = 0; w < 4; ++w)
        if (w < wid) add += wsum[w];
    return v + add;
}

// ---------------------------------------------------------------- CSR build
// 4 edges per thread (int4) -> 1/4 the wave count
__global__ void hist_kernel(const int* __restrict__ ei, int* __restrict__ rowptr) {
    int e4 = (blockIdx.x * blockDim.x + threadIdx.x) * 4;
    if (e4 < NE) {
        int4 d = *(const int4*)&ei[NE + e4];
        atomicAdd(&rowptr[d.x + 1], 1);
        atomicAdd(&rowptr[d.y + 1], 1);
        atomicAdd(&rowptr[d.z + 1], 1);
        atomicAdd(&rowptr[d.w + 1], 1);
    }
}

// phase 1: local inclusive scan of rowptr[1..NN], block totals out
__global__ __launch_bounds__(SCAN_T) void scan1(int* __restrict__ rowptr,
                                                int* __restrict__ blockSums) {
    int i = blockIdx.x * SCAN_T + threadIdx.x;
    int v = (i < NN) ? rowptr[1 + i] : 0;
    v = block_iscan(v, threadIdx.x);
    if (i < NN) rowptr[1 + i] = v;
    if (threadIdx.x == SCAN_T - 1) blockSums[blockIdx.x] = v;
}

// phase 2: exclusive scan of block totals (196 <= 256, one block)
__global__ __launch_bounds__(SCAN_T) void scan2(int* __restrict__ blockSums) {
    int t = threadIdx.x;
    int orig = (t < SCAN_B) ? blockSums[t] : 0;
    int v = block_iscan(orig, t);
    if (t < SCAN_B) blockSums[t] = v - orig;   // exclusive
}

// phase 3: add block offsets; emit cursor[] (exclusive prefix per node)
__global__ __launch_bounds__(SCAN_T) void scan3(int* __restrict__ rowptr,
                                                const int* __restrict__ blockSums,
                                                int* __restrict__ cursor) {
    int i = blockIdx.x * SCAN_T + threadIdx.x;
    if (i < NN) {
        int v = rowptr[1 + i] + blockSums[blockIdx.x];
        rowptr[1 + i] = v;
        if (i + 1 < NN) cursor[i + 1] = v;
    }
    if (i == 0) cursor[0] = 0;
}

// single packed CSR payload: csr[pos] = {src, eid, w_bits, 0}
__global__ void fill_kernel(const int* __restrict__ ei, const float* __restrict__ ew,
                            int* __restrict__ cursor, uint4* __restrict__ csr) {
    int e = blockIdx.x * blockDim.x + threadIdx.x;
    if (e < NE) {
        int d = ei[NE + e];
        int pos = atomicAdd(&cursor[d], 1);
        uint4 q;
        q.x = (unsigned int)ei[e];
        q.y = (unsigned int)e;
        q.z = __float_as_uint(ew[e]);
        q.w = 0;
        csr[pos] = q;
    }
}

// ---- prep: fused cast_x + inc. Wave per node; inc gather 4-deep per group.
__global__ __launch_bounds__(256) void prep_kernel(
    const float* __restrict__ x,
    const float* __restrict__ edge_attr,
    const int* __restrict__ rowptr,
    const uint4* __restrict__ csr,
    unsigned short* __restrict__ A1) {
    int n = (blockIdx.x * blockDim.x + threadIdx.x) >> 6;
    int lane = threadIdx.x & 63;
    if (n >= NN) return;

    float2 v = *(const float2*)&x[(size_t)n * ND + lane * 2];
    unsigned int o = (unsigned int)f2b(v.x) | ((unsigned int)f2b(v.y) << 16);
    *(unsigned int*)&A1[(size_t)n * KP1 + lane * 2] = o;

    int g = lane >> 4, j = lane & 15;
    int lo = rowptr[n], hi = rowptr[n + 1];
    float s = 0.f;
    for (int k = lo + g; k < hi; k += 16) {       // 4 edges per group in flight
        int k1 = (k + 4  < hi) ? k + 4  : k;
        int k2 = (k + 8  < hi) ? k + 8  : k;
        int k3 = (k + 12 < hi) ? k + 12 : k;
        uint4 e0 = csr[k],  e1 = csr[k1];
        uint4 e2 = csr[k2], e3 = csr[k3];
        float a0 = edge_attr[(size_t)e0.y * ED + j];
        float a1 = edge_attr[(size_t)e1.y * ED + j];
        float a2 = edge_attr[(size_t)e2.y * ED + j];
        float a3 = edge_attr[(size_t)e3.y * ED + j];
        s += __uint_as_float(e0.z) * a0;
        s += ((k + 4  < hi) ? __uint_as_float(e1.z) : 0.f) * a1;
        s += ((k + 8  < hi) ? __uint_as_float(e2.z) : 0.f) * a2;
        s += ((k + 12 < hi) ? __uint_as_float(e3.z) : 0.f) * a3;
    }
    s += __shfl_xor(s, 16);
    s += __shfl_xor(s, 32);
    if (lane < 16)
        A1[(size_t)n * KP1 + ND + lane] = f2b(s);
    else
        A1[(size_t)n * KP1 + ND + lane] = 0;      // pad cols 144..191
}

// B0T[n][k] = bf16(W0[k][n]) padded to [320][192]
__global__ void castB0(const float* __restrict__ W0, unsigned short* __restrict__ B0T) {
    int n = blockIdx.x, k = threadIdx.x;
    float v = (n < HID && k < ND + ED) ? W0[(size_t)k * HID + n] : 0.f;
    B0T[(size_t)n * KP1 + k] = f2b(v);
}

// BT[n][k] = bf16(W[k][n]) padded to [320][320]
__global__ void castB(const float* __restrict__ W, unsigned short* __restrict__ BT) {
    int n = blockIdx.x, k = threadIdx.x;
    float v = (n < HID && k < HID) ? W[(size_t)k * HID + n] : 0.f;
    BT[(size_t)n * KP2 + k] = f2b(v);
}

// --------------------------------------------- persistent stream-M MFMA GEMM
// ROUND-6 structure (best measured): 256 threads (4 waves), 1 block/CU.
// B panel staged in LDS (XOR-swizzled, rule 21); A streamed in 32-row tiles,
// double-buffered via global_load_lds; one __syncthreads per tile whose
// vmcnt(0) drain is covered by ~2000cy of compute+epilogue.
// NEW: NY>1 loops N-panels INSIDE the block (re-stages B between passes) so
// A is fetched from HBM only once instead of once per N-panel.
template <int MODE, int KP, int BN, int WM, int WN, int RPB, int NY>
__global__ __launch_bounds__(256) void gemm_stream(
    const unsigned short* __restrict__ A,   // [M, KP] bf16 row-major
    const unsigned short* __restrict__ BT,  // [320, KP] bf16 (B transposed)
    const float* __restrict__ bias,         // [300]
    const float* __restrict__ RES,          // MODE1: h0 [M,300] fp32
    float* __restrict__ C,                  // [M,300] fp32
    unsigned short* __restrict__ h0b,       // MODE0: [M,320] bf16
    int M)
{
    constexpr int CPR = KP / 8;          // 16B chunks per row
    constexpr int ACH = 32 * CPR;        // chunks per A buffer
    constexpr int BCH = BN * CPR;        // chunks in B panel
    constexpr int AM  = 32 / (16 * WM);  // a-frags per wave
    constexpr int BNW = BN / (16 * WN);  // b-frags per wave (=5)
    __shared__ unsigned short Bs[BCH * 8];     // g1:120KB g2:100KB
    __shared__ unsigned short As[2][ACH * 8];  // g1:24KB  g2:40KB

    const int tid = threadIdx.x;
    const int wave = tid >> 6, lane = tid & 63;
    const int wm = wave / WN, wn = wave % WN;
    const int quad = lane >> 4, lr = lane & 15;
    const int rbase = blockIdx.x * RPB;
    const int rowend = min(rbase + RPB, M);
    const int nt = (rowend - rbase + 31) >> 5;

    auto stageA = [&](int buf, int mb) {
        #pragma unroll
        for (int rd = 0; rd < ACH / 256; ++rd) {
            int s = rd * 256 + tid;
            int row = s / CPR, c = s - row * CPR;
            int cs = (c & ~7) | ((c & 7) ^ (row & 7));
            int mg = mb + row; if (mg >= M) mg = M - 1;
            gload16(&A[(size_t)mg * KP + cs * 8], &As[buf][s * 8]);
        }
    };

    #pragma unroll 1
    for (int ny = 0; ny < NY; ++ny) {
        const int n00 = ny * BN;
        const int ncol = n00 + wn * (BNW * 16);

        // ---- stage B panel (swizzled source, linear dest)
        #pragma unroll
        for (int rd = 0; rd < BCH / 256; ++rd) {
            int s = rd * 256 + tid;
            int row = s / CPR, c = s - row * CPR;
            int cs = (c & ~7) | ((c & 7) ^ (row & 7));
            gload16(&BT[(size_t)(n00 + row) * KP + cs * 8], &Bs[s * 8]);
        }
        stageA(0, rbase);

        float bias_r[BNW];
        #pragma unroll
        for (int tn = 0; tn < BNW; ++tn) {
            int ng = ncol + tn * 16 + lr;
            bias_r[tn] = (ng < HID) ? bias[ng] : 0.f;
        }
        __syncthreads();   // drains vmcnt(0): B panel + first A tile resident

        int cur = 0;
        #pragma unroll 1
        for (int t = 0; t < nt; ++t) {
            const int mb = rbase + t * 32;
            if (t + 1 < nt) stageA(cur ^ 1, mb + 32);   // prefetch next tile

            float res_r[AM][BNW][4];
            if (MODE == 1) {   // residual prefetch; latency hidden by compute
                #pragma unroll
                for (int tm = 0; tm < AM; ++tm)
                #pragma unroll
                for (int tn = 0; tn < BNW; ++tn) {
                    int ng = ncol + tn * 16 + lr;
                    int ngc = ng < HID ? ng : HID - 1;
                    #pragma unroll
                    for (int r = 0; r < 4; ++r) {
                        int mg = mb + (wm * AM + tm) * 16 + quad * 4 + r;
                        int mgc = mg < M ? mg : M - 1;
                        res_r[tm][tn][r] = RES[(size_t)mgc * HID + ngc];
                    }
                }
            }

            f32x4 acc[AM][BNW] = {};
            const int rm = lr & 7;
            #pragma unroll
            for (int tt = 0; tt < KP / 32; ++tt) {
                int cA = tt * 4 + quad;
                int sw8 = ((cA & ~7) | ((cA & 7) ^ rm)) * 8;
                short8 a[AM], b[BNW];
                #pragma unroll
                for (int tm = 0; tm < AM; ++tm) {
                    int ar = (wm * AM + tm) * 16 + lr;
                    a[tm] = *(const short8*)&As[cur][ar * KP + sw8];
                }
                #pragma unroll
                for (int tn = 0; tn < BNW; ++tn) {
                    int br = wn * (BNW * 16) + tn * 16 + lr;
                    b[tn] = *(const short8*)&Bs[br * KP + sw8];
                }
                #pragma unroll
                for (int tm = 0; tm < AM; ++tm)
                    #pragma unroll
                    for (int tn = 0; tn < BNW; ++tn)
                        acc[tm][tn] = __builtin_amdgcn_mfma_f32_16x16x32_bf16(
                            a[tm], b[tn], acc[tm][tn], 0, 0, 0);
            }

            #pragma unroll
            for (int tm = 0; tm < AM; ++tm)
            #pragma unroll
            for (int tn = 0; tn < BNW; ++tn) {
                int ng = ncol + tn * 16 + lr;
                #pragma unroll
                for (int r = 0; r < 4; ++r) {
                    int mg = mb + (wm * AM + tm) * 16 + quad * 4 + r;
                    if (mg < rowend && ng < HID) {
                        float v = acc[tm][tn][r] + bias_r[tn];
                        if (MODE == 1) v += res_r[tm][tn][r];
                        v = fmaxf(v, 0.f);
                        C[(size_t)mg * HID + ng] = v;
                        if (MODE == 0) h0b[(size_t)mg * NP + ng] = f2b(v);
                    }
                }
            }
            __syncthreads();   // next-tile stage (issued pre-compute) drained
            cur ^= 1;
        }
    }
}

// ---------------- aggB[n] = bf16(mean_k w_k * h0b[src_k]) ------------------
__device__ __forceinline__ void acc8(float* acc, float w, const uint4& r) {
    acc[0] += w * blo(r.x); acc[1] += w * bhi(r.x);
    acc[2] += w * blo(r.y); acc[3] += w * bhi(r.y);
    acc[4] += w * blo(r.z); acc[5] += w * bhi(r.z);
    acc[6] += w * blo(r.w); acc[7] += w * bhi(r.w);
}

// wave per node; 40 lanes x 16B cover the 640B row; EIGHT gathered rows in
// flight (latency-bound gather), clamp-predicated -- no serial tail.
// Fully unrolled so all indices are compile-time (rule #20).
__global__ __launch_bounds__(256) void agg_kernel(
    const unsigned short* __restrict__ h0b,   // [NN, 320] bf16
    const int* __restrict__ rowptr,
    const uint4* __restrict__ csr,
    unsigned short* __restrict__ aggB)        // [NN, 320] bf16, pad cols = 0
{
    int n = (blockIdx.x * blockDim.x + threadIdx.x) >> 6;
    int lane = threadIdx.x & 63;
    if (n >= NN) return;
    int lo = rowptr[n], hi = rowptr[n + 1];
    float acc[8] = {};
    const uint4* h4 = (const uint4*)h0b;      // row stride = 40 uint4
    bool act = lane < 40;
    for (int k = lo; k < hi; k += 8) {        // 8-deep, clamp-predicated
        uint4 p0 = csr[k];
        uint4 p1 = csr[(k + 1 < hi) ? k + 1 : k];
        uint4 p2 = csr[(k + 2 < hi) ? k + 2 : k];
        uint4 p3 = csr[(k + 3 < hi) ? k + 3 : k];
        uint4 p4 = csr[(k + 4 < hi) ? k + 4 : k];
        uint4 p5 = csr[(k + 5 < hi) ? k + 5 : k];
        uint4 p6 = csr[(k + 6 < hi) ? k + 6 : k];
        uint4 p7 = csr[(k + 7 < hi) ? k + 7 : k];
        float w0 = __uint_as_float(p0.z);
        float w1 = (k + 1 < hi) ? __uint_as_float(p1.z) : 0.f;
        float w2 = (k + 2 < hi) ? __uint_as_float(p2.z) : 0.f;
        float w3 = (k + 3 < hi) ? __uint_as_float(p3.z) : 0.f;
        float w4 = (k + 4 < hi) ? __uint_as_float(p4.z) : 0.f;
        float w5 = (k + 5 < hi) ? __uint_as_float(p5.z) : 0.f;
        float w6 = (k + 6 < hi) ? __uint_as_float(p6.z) : 0.f;
        float w7 = (k + 7 < hi) ? __uint_as_float(p7.z) : 0.f;
        uint4 r0 = {0,0,0,0}, r1 = {0,0,0,0}, r2 = {0,0,0,0}, r3 = {0,0,0,0};
        uint4 r4 = {0,0,0,0}, r5 = {0,0,0,0}, r6 = {0,0,0,0}, r7 = {0,0,0,0};
        if (act) {
            r0 = h4[(size_t)p0.x * 40 + lane];
            r1 = h4[(size_t)p1.x * 40 + lane];
            r2 = h4[(size_t)p2.x * 40 + lane];
            r3 = h4[(size_t)p3.x * 40 + lane];
            r4 = h4[(size_t)p4.x * 40 + lane];
            r5 = h4[(size_t)p5.x * 40 + lane];
            r6 = h4[(size_t)p6.x * 40 + lane];
            r7 = h4[(size_t)p7.x * 40 + lane];
        }
        acc8(acc, w0, r0); acc8(acc, w1, r1);
        acc8(acc, w2, r2); acc8(acc, w3, r3);
        acc8(acc, w4, r4); acc8(acc, w5, r5);
        acc8(acc, w6, r6); acc8(acc, w7, r7);
    }
    if (act) {
        float invd = 1.f / fmaxf((float)(hi - lo), 1.f);
        int cbase = lane * 8;
        unsigned int o[4];
        #pragma unroll
        for (int i = 0; i < 4; ++i) {
            int c0 = cbase + 2 * i, c1 = c0 + 1;
            unsigned int ulo = (c0 < HID) ? f2b(acc[2 * i] * invd) : 0;
            unsigned int uhi = (c1 < HID) ? f2b(acc[2 * i + 1] * invd) : 0;
            o[i] = ulo | (uhi << 16);
        }
        uint4* a4 = (uint4*)aggB;
        uint4 v; v.x = o[0]; v.y = o[1]; v.z = o[2]; v.w = o[3];
        a4[(size_t)n * 40 + lane] = v;
    }
}

// ---------------------------------------------------------------- launch
extern "C" void kernel_launch(void* const* d_in, const int* in_sizes, int n_in,
                              void* d_out, int out_size, void* d_ws, size_t ws_size,
                              hipStream_t stream) {
    const float* x           = (const float*)d_in[0];
    const float* edge_attr   = (const float*)d_in[1];
    const float* edge_weight = (const float*)d_in[2];
    const float* W0 = (const float*)d_in[4];
    const float* b0 = (const float*)d_in[5];
    const float* W  = (const float*)d_in[6];
    const float* b  = (const float*)d_in[7];
    const int* ei   = (const int*)d_in[8];

    float* out = (float*)d_out;
    float* h  = out;                          // output 0: [NN, HID]
    float* h0 = out + (size_t)NN * HID;       // output 1: [NN, HID]

    char* p = (char*)d_ws;
    auto alloc = [&](size_t bytes) { char* q = p; p += (bytes + 255) & ~(size_t)255; return q; };
    int*   rowptr  = (int*)  alloc((NN + 1) * sizeof(int));
    int*   cursor  = (int*)  alloc(NN * sizeof(int));
    int*   bsums   = (int*)  alloc(SCAN_B * sizeof(int));
    uint4* csr     = (uint4*)alloc((size_t)NE * sizeof(uint4));
    unsigned short* A1   = (unsigned short*)alloc((size_t)NN * KP1 * 2);
    unsigned short* h0b  = (unsigned short*)alloc((size_t)NN * NP * 2);
    unsigned short* aggB = (unsigned short*)alloc((size_t)NN * NP * 2);
    unsigned short* B0T  = (unsigned short*)alloc((size_t)NP * KP1 * 2);
    unsigned short* BT   = (unsigned short*)alloc((size_t)NP * KP2 * 2);

    hipMemsetAsync(rowptr, 0, (NN + 1) * sizeof(int), stream);
    hist_kernel<<<(NE / 4 + 255) / 256, 256, 0, stream>>>(ei, rowptr);
    scan1<<<SCAN_B, SCAN_T, 0, stream>>>(rowptr, bsums);
    scan2<<<1, SCAN_T, 0, stream>>>(bsums);
    scan3<<<SCAN_B, SCAN_T, 0, stream>>>(rowptr, bsums, cursor);
    fill_kernel<<<(NE + 255) / 256, 256, 0, stream>>>(ei, edge_weight, cursor, csr);
    castB0<<<NP, KP1, 0, stream>>>(W0, B0T);
    castB<<<NP, KP2, 0, stream>>>(W, BT);
    prep_kernel<<<(NN + 3) / 4, 256, 0, stream>>>(x, edge_attr, rowptr, csr, A1);

    // gemm1: 256 blocks (1/CU), 4 waves, full N=320 panel, 32-row dbuf tiles
    gemm_stream<0, KP1, 320, 1, 4, 196, 1><<<dim3(256, 1), 256, 0, stream>>>(
        A1, B0T, b0, nullptr, h0, h0b, NN);
    agg_kernel<<<(NN + 3) / 4, 256, 0, stream>>>(h0b, rowptr, csr, aggB);
    // gemm2: 256 blocks (1/CU), N-halves looped IN-BLOCK (aggB read once)
    gemm_stream<1, KP2, 160, 2, 2, 196, 2><<<dim3(256, 1), 256, 0, stream>>>(
        aggB, BT, b, h0, h, nullptr, NN);
}

// Round 10
// 442.452 us; speedup vs baseline: 1.0648x; 1.0345x over previous
//
#include <hip/hip_runtime.h>

#define NN 50000      // nodes
#define NE 800000     // edges
#define ND 128        // node_attr_dim
#define ED 16         // edge_attr_dim
#define HID 300       // hidden
#define KP1 192       // padded K for gemm1 (128+16 -> 192)
#define KP2 320       // padded K for gemm2 (300 -> 320)
#define NP 320        // padded N (300 -> 320)

#define SCAN_T 256
#define SCAN_B ((NN + SCAN_T - 1) / SCAN_T)   // 196 blocks

typedef __attribute__((ext_vector_type(8))) short short8;
typedef __attribute__((ext_vector_type(4))) float f32x4;

__device__ __forceinline__ unsigned short f2b(float f) {
    unsigned int u = __float_as_uint(f);
    u = (u + 0x7FFFu + ((u >> 16) & 1u)) >> 16;   // RNE
    return (unsigned short)u;
}
__device__ __forceinline__ float blo(unsigned int u) {
    return __uint_as_float(u << 16);
}
__device__ __forceinline__ float bhi(unsigned int u) {
    return __uint_as_float(u & 0xffff0000u);
}

// async global->LDS: 16B per lane, dest = wave-uniform base + lane*16
__device__ __forceinline__ void gload16(const void* g, void* l) {
    __builtin_amdgcn_global_load_lds(
        (const __attribute__((address_space(1))) void*)g,
        (__attribute__((address_space(3))) void*)l, 16, 0, 0);
}

// in-block inclusive scan of v across 256 threads (4 waves)
__device__ __forceinline__ int block_iscan(int v, int tid) {
    int lane = tid & 63;
    #pragma unroll
    for (int off = 1; off < 64; off <<= 1) {
        int t = __shfl_up(v, off);
        if (lane >= off) v += t;
    }
    __shared__ int wsum[4];
    int wid = tid >> 6;
    if (lane == 63) wsum[wid] = v;
    __syncthreads();
    int add = 0;
    #pragma unroll
    for (int w = 0; w < 4; ++w)
        if (w < wid) add += wsum[w];
    return v + add;
}

// ---------------------------------------------------------------- CSR build
// 4 edges per thread (int4) -> 1/4 the wave count
__global__ void hist_kernel(const int* __restrict__ ei, int* __restrict__ rowptr) {
    int e4 = (blockIdx.x * blockDim.x + threadIdx.x) * 4;
    if (e4 < NE) {
        int4 d = *(const int4*)&ei[NE + e4];
        atomicAdd(&rowptr[d.x + 1], 1);
        atomicAdd(&rowptr[d.y + 1], 1);
        atomicAdd(&rowptr[d.z + 1], 1);
        atomicAdd(&rowptr[d.w + 1], 1);
    }
}

// phase 1: local inclusive scan of rowptr[1..NN], block totals out
__global__ __launch_bounds__(SCAN_T) void scan1(int* __restrict__ rowptr,
                                                int* __restrict__ blockSums) {
    int i = blockIdx.x * SCAN_T + threadIdx.x;
    int v = (i < NN) ? rowptr[1 + i] : 0;
    v = block_iscan(v, threadIdx.x);
    if (i < NN) rowptr[1 + i] = v;
    if (threadIdx.x == SCAN_T - 1) blockSums[blockIdx.x] = v;
}

// phase 2: exclusive scan of block totals (196 <= 256, one block)
__global__ __launch_bounds__(SCAN_T) void scan2(int* __restrict__ blockSums) {
    int t = threadIdx.x;
    int orig = (t < SCAN_B) ? blockSums[t] : 0;
    int v = block_iscan(orig, t);
    if (t < SCAN_B) blockSums[t] = v - orig;   // exclusive
}

// phase 3: add block offsets; emit cursor[] (exclusive prefix per node)
__global__ __launch_bounds__(SCAN_T) void scan3(int* __restrict__ rowptr,
                                                const int* __restrict__ blockSums,
                                                int* __restrict__ cursor) {
    int i = blockIdx.x * SCAN_T + threadIdx.x;
    if (i < NN) {
        int v = rowptr[1 + i] + blockSums[blockIdx.x];
        rowptr[1 + i] = v;
        if (i + 1 < NN) cursor[i + 1] = v;
    }
    if (i == 0) cursor[0] = 0;
}

// single packed CSR payload: csr[pos] = {src, eid, w_bits, 0}
__global__ void fill_kernel(const int* __restrict__ ei, const float* __restrict__ ew,
                            int* __restrict__ cursor, uint4* __restrict__ csr) {
    int e = blockIdx.x * blockDim.x + threadIdx.x;
    if (e < NE) {
        int d = ei[NE + e];
        int pos = atomicAdd(&cursor[d], 1);
        uint4 q;
        q.x = (unsigned int)ei[e];
        q.y = (unsigned int)e;
        q.z = __float_as_uint(ew[e]);
        q.w = 0;
        csr[pos] = q;
    }
}

// ---- prep: fused cast_x + inc. Wave per node; inc gather 4-deep per group.
__global__ __launch_bounds__(256) void prep_kernel(
    const float* __restrict__ x,
    const float* __restrict__ edge_attr,
    const int* __restrict__ rowptr,
    const uint4* __restrict__ csr,
    unsigned short* __restrict__ A1) {
    int n = (blockIdx.x * blockDim.x + threadIdx.x) >> 6;
    int lane = threadIdx.x & 63;
    if (n >= NN) return;

    float2 v = *(const float2*)&x[(size_t)n * ND + lane * 2];
    unsigned int o = (unsigned int)f2b(v.x) | ((unsigned int)f2b(v.y) << 16);
    *(unsigned int*)&A1[(size_t)n * KP1 + lane * 2] = o;

    int g = lane >> 4, j = lane & 15;
    int lo = rowptr[n], hi = rowptr[n + 1];
    float s = 0.f;
    for (int k = lo + g; k < hi; k += 16) {       // 4 edges per group in flight
        int k1 = (k + 4  < hi) ? k + 4  : k;
        int k2 = (k + 8  < hi) ? k + 8  : k;
        int k3 = (k + 12 < hi) ? k + 12 : k;
        uint4 e0 = csr[k],  e1 = csr[k1];
        uint4 e2 = csr[k2], e3 = csr[k3];
        float a0 = edge_attr[(size_t)e0.y * ED + j];
        float a1 = edge_attr[(size_t)e1.y * ED + j];
        float a2 = edge_attr[(size_t)e2.y * ED + j];
        float a3 = edge_attr[(size_t)e3.y * ED + j];
        s += __uint_as_float(e0.z) * a0;
        s += ((k + 4  < hi) ? __uint_as_float(e1.z) : 0.f) * a1;
        s += ((k + 8  < hi) ? __uint_as_float(e2.z) : 0.f) * a2;
        s += ((k + 12 < hi) ? __uint_as_float(e3.z) : 0.f) * a3;
    }
    s += __shfl_xor(s, 16);
    s += __shfl_xor(s, 32);
    if (lane < 16)
        A1[(size_t)n * KP1 + ND + lane] = f2b(s);
    else
        A1[(size_t)n * KP1 + ND + lane] = 0;      // pad cols 144..191
}

// B0T[n][k] = bf16(W0[k][n]) padded to [320][192]
__global__ void castB0(const float* __restrict__ W0, unsigned short* __restrict__ B0T) {
    int n = blockIdx.x, k = threadIdx.x;
    float v = (n < HID && k < ND + ED) ? W0[(size_t)k * HID + n] : 0.f;
    B0T[(size_t)n * KP1 + k] = f2b(v);
}

// BT[n][k] = bf16(W[k][n]) padded to [320][320]
__global__ void castB(const float* __restrict__ W, unsigned short* __restrict__ BT) {
    int n = blockIdx.x, k = threadIdx.x;
    float v = (n < HID && k < HID) ? W[(size_t)k * HID + n] : 0.f;
    BT[(size_t)n * KP2 + k] = f2b(v);
}

// --------------------------------------------- persistent stream-M MFMA GEMM
// Round-6 structure; THR now a template param. gemm1 runs 512 threads
// (8 waves = 2/SIMD): Bs 120KB + As dbuf 24KB = 144KB fits, and the per-tile
// barrier drain is now covered by a second wave per SIMD. gemm2 stays at the
// r6-measured 256-thr/(128,2) config (100KB B panel forbids 512-thr dbuf).
template <int MODE, int KP, int BN, int WM, int WN, int RPB, int THR>
__global__ __launch_bounds__(THR) void gemm_stream(
    const unsigned short* __restrict__ A,   // [M, KP] bf16 row-major
    const unsigned short* __restrict__ BT,  // [320, KP] bf16 (B transposed)
    const float* __restrict__ bias,         // [300]
    const float* __restrict__ RES,          // MODE1: h0 [M,300] fp32
    float* __restrict__ C,                  // [M,300] fp32
    unsigned short* __restrict__ h0b,       // MODE0: [M,320] bf16
    int M)
{
    constexpr int CPR = KP / 8;          // 16B chunks per row
    constexpr int ACH = 32 * CPR;        // chunks per A buffer
    constexpr int BCH = BN * CPR;        // chunks in B panel
    constexpr int NW  = THR / 64;        // waves
    constexpr int AM  = 32 / (16 * WM);  // a-frags per wave
    constexpr int BNW = BN / (16 * WN);  // b-frags per wave (=5)
    static_assert(WM * WN == NW, "wave grid must cover block");
    __shared__ unsigned short Bs[BCH * 8];     // g1:120KB g2:100KB
    __shared__ unsigned short As[2][ACH * 8];  // g1:24KB  g2:40KB

    const int tid = threadIdx.x;
    const int wave = tid >> 6, lane = tid & 63;
    const int wm = wave / WN, wn = wave % WN;
    const int quad = lane >> 4, lr = lane & 15;
    const int n00 = blockIdx.y * BN;
    const int ncol = n00 + wn * (BNW * 16);
    const int rbase = blockIdx.x * RPB;
    const int rowend = min(rbase + RPB, M);
    const int nt = (rowend - rbase + 31) >> 5;

    auto stageA = [&](int buf, int mb) {
        for (int s = tid; s < ACH; s += THR) {
            int row = s / CPR, c = s - row * CPR;
            int cs = (c & ~7) | ((c & 7) ^ (row & 7));
            int mg = mb + row; if (mg >= M) mg = M - 1;
            gload16(&A[(size_t)mg * KP + cs * 8], &As[buf][s * 8]);
        }
    };

    // ---- stage B panel once (swizzled source, linear dest)
    for (int s = tid; s < BCH; s += THR) {
        int row = s / CPR, c = s - row * CPR;
        int cs = (c & ~7) | ((c & 7) ^ (row & 7));
        gload16(&BT[(size_t)(n00 + row) * KP + cs * 8], &Bs[s * 8]);
    }
    stageA(0, rbase);

    float bias_r[BNW];
    #pragma unroll
    for (int tn = 0; tn < BNW; ++tn) {
        int ng = ncol + tn * 16 + lr;
        bias_r[tn] = (ng < HID) ? bias[ng] : 0.f;
    }
    __syncthreads();   // drains vmcnt(0): B panel + first A tile resident

    int cur = 0;
    #pragma unroll 1
    for (int t = 0; t < nt; ++t) {
        const int mb = rbase + t * 32;
        if (t + 1 < nt) stageA(cur ^ 1, mb + 32);   // prefetch next tile

        float res_r[AM][BNW][4];
        if (MODE == 1) {   // residual prefetch; latency hidden by compute
            #pragma unroll
            for (int tm = 0; tm < AM; ++tm)
            #pragma unroll
            for (int tn = 0; tn < BNW; ++tn) {
                int ng = ncol + tn * 16 + lr;
                int ngc = ng < HID ? ng : HID - 1;
                #pragma unroll
                for (int r = 0; r < 4; ++r) {
                    int mg = mb + (wm * AM + tm) * 16 + quad * 4 + r;
                    int mgc = mg < M ? mg : M - 1;
                    res_r[tm][tn][r] = RES[(size_t)mgc * HID + ngc];
                }
            }
        }

        f32x4 acc[AM][BNW] = {};
        const int rm = lr & 7;
        #pragma unroll
        for (int tt = 0; tt < KP / 32; ++tt) {
            int cA = tt * 4 + quad;
            int sw8 = ((cA & ~7) | ((cA & 7) ^ rm)) * 8;
            short8 a[AM], b[BNW];
            #pragma unroll
            for (int tm = 0; tm < AM; ++tm) {
                int ar = (wm * AM + tm) * 16 + lr;
                a[tm] = *(const short8*)&As[cur][ar * KP + sw8];
            }
            #pragma unroll
            for (int tn = 0; tn < BNW; ++tn) {
                int br = wn * (BNW * 16) + tn * 16 + lr;
                b[tn] = *(const short8*)&Bs[br * KP + sw8];
            }
            #pragma unroll
            for (int tm = 0; tm < AM; ++tm)
                #pragma unroll
                for (int tn = 0; tn < BNW; ++tn)
                    acc[tm][tn] = __builtin_amdgcn_mfma_f32_16x16x32_bf16(
                        a[tm], b[tn], acc[tm][tn], 0, 0, 0);
        }

        #pragma unroll
        for (int tm = 0; tm < AM; ++tm)
        #pragma unroll
        for (int tn = 0; tn < BNW; ++tn) {
            int ng = ncol + tn * 16 + lr;
            #pragma unroll
            for (int r = 0; r < 4; ++r) {
                int mg = mb + (wm * AM + tm) * 16 + quad * 4 + r;
                if (mg < rowend && ng < HID) {
                    float v = acc[tm][tn][r] + bias_r[tn];
                    if (MODE == 1) v += res_r[tm][tn][r];
                    v = fmaxf(v, 0.f);
                    C[(size_t)mg * HID + ng] = v;
                    if (MODE == 0) h0b[(size_t)mg * NP + ng] = f2b(v);
                }
            }
        }
        __syncthreads();   // next-tile stage (issued pre-compute) drained
        cur ^= 1;
    }
}

// ---------------- aggB[n] = bf16(mean_k w_k * h0b[src_k]) ------------------
__device__ __forceinline__ void acc8(float* acc, float w, const uint4& r) {
    acc[0] += w * blo(r.x); acc[1] += w * bhi(r.x);
    acc[2] += w * blo(r.y); acc[3] += w * bhi(r.y);
    acc[4] += w * blo(r.z); acc[5] += w * bhi(r.z);
    acc[6] += w * blo(r.w); acc[7] += w * bhi(r.w);
}

// wave per node; 40 lanes x 16B cover the 640B row; FOUR gathered rows in
// flight, clamp-predicated (r6-measured config; 8-deep regressed in r9).
__global__ __launch_bounds__(256) void agg_kernel(
    const unsigned short* __restrict__ h0b,   // [NN, 320] bf16
    const int* __restrict__ rowptr,
    const uint4* __restrict__ csr,
    unsigned short* __restrict__ aggB)        // [NN, 320] bf16, pad cols = 0
{
    int n = (blockIdx.x * blockDim.x + threadIdx.x) >> 6;
    int lane = threadIdx.x & 63;
    if (n >= NN) return;
    int lo = rowptr[n], hi = rowptr[n + 1];
    float acc[8] = {};
    const uint4* h4 = (const uint4*)h0b;      // row stride = 40 uint4
    bool act = lane < 40;
    for (int k = lo; k < hi; k += 4) {        // 4-deep, clamp-predicated
        uint4 p0 = csr[k];
        uint4 p1 = csr[(k + 1 < hi) ? k + 1 : k];
        uint4 p2 = csr[(k + 2 < hi) ? k + 2 : k];
        uint4 p3 = csr[(k + 3 < hi) ? k + 3 : k];
        float w0 = __uint_as_float(p0.z);
        float w1 = (k + 1 < hi) ? __uint_as_float(p1.z) : 0.f;
        float w2 = (k + 2 < hi) ? __uint_as_float(p2.z) : 0.f;
        float w3 = (k + 3 < hi) ? __uint_as_float(p3.z) : 0.f;
        uint4 r0 = {0,0,0,0}, r1 = {0,0,0,0}, r2 = {0,0,0,0}, r3 = {0,0,0,0};
        if (act) {
            r0 = h4[(size_t)p0.x * 40 + lane];
            r1 = h4[(size_t)p1.x * 40 + lane];
            r2 = h4[(size_t)p2.x * 40 + lane];
            r3 = h4[(size_t)p3.x * 40 + lane];
        }
        acc8(acc, w0, r0); acc8(acc, w1, r1);
        acc8(acc, w2, r2); acc8(acc, w3, r3);
    }
    if (act) {
        float invd = 1.f / fmaxf((float)(hi - lo), 1.f);
        int cbase = lane * 8;
        unsigned int o[4];
        #pragma unroll
        for (int i = 0; i < 4; ++i) {
            int c0 = cbase + 2 * i, c1 = c0 + 1;
            unsigned int ulo = (c0 < HID) ? f2b(acc[2 * i] * invd) : 0;
            unsigned int uhi = (c1 < HID) ? f2b(acc[2 * i + 1] * invd) : 0;
            o[i] = ulo | (uhi << 16);
        }
        uint4* a4 = (uint4*)aggB;
        uint4 v; v.x = o[0]; v.y = o[1]; v.z = o[2]; v.w = o[3];
        a4[(size_t)n * 40 + lane] = v;
    }
}

// ---------------------------------------------------------------- launch
extern "C" void kernel_launch(void* const* d_in, const int* in_sizes, int n_in,
                              void* d_out, int out_size, void* d_ws, size_t ws_size,
                              hipStream_t stream) {
    const float* x           = (const float*)d_in[0];
    const float* edge_attr   = (const float*)d_in[1];
    const float* edge_weight = (const float*)d_in[2];
    const float* W0 = (const float*)d_in[4];
    const float* b0 = (const float*)d_in[5];
    const float* W  = (const float*)d_in[6];
    const float* b  = (const float*)d_in[7];
    const int* ei   = (const int*)d_in[8];

    float* out = (float*)d_out;
    float* h  = out;                          // output 0: [NN, HID]
    float* h0 = out + (size_t)NN * HID;       // output 1: [NN, HID]

    char* p = (char*)d_ws;
    auto alloc = [&](size_t bytes) { char* q = p; p += (bytes + 255) & ~(size_t)255; return q; };
    int*   rowptr  = (int*)  alloc((NN + 1) * sizeof(int));
    int*   cursor  = (int*)  alloc(NN * sizeof(int));
    int*   bsums   = (int*)  alloc(SCAN_B * sizeof(int));
    uint4* csr     = (uint4*)alloc((size_t)NE * sizeof(uint4));
    unsigned short* A1   = (unsigned short*)alloc((size_t)NN * KP1 * 2);
    unsigned short* h0b  = (unsigned short*)alloc((size_t)NN * NP * 2);
    unsigned short* aggB = (unsigned short*)alloc((size_t)NN * NP * 2);
    unsigned short* B0T  = (unsigned short*)alloc((size_t)NP * KP1 * 2);
    unsigned short* BT   = (unsigned short*)alloc((size_t)NP * KP2 * 2);

    hipMemsetAsync(rowptr, 0, (NN + 1) * sizeof(int), stream);
    hist_kernel<<<(NE / 4 + 255) / 256, 256, 0, stream>>>(ei, rowptr);
    scan1<<<SCAN_B, SCAN_T, 0, stream>>>(rowptr, bsums);
    scan2<<<1, SCAN_T, 0, stream>>>(bsums);
    scan3<<<SCAN_B, SCAN_T, 0, stream>>>(rowptr, bsums, cursor);
    fill_kernel<<<(NE + 255) / 256, 256, 0, stream>>>(ei, edge_weight, cursor, csr);
    castB0<<<NP, KP1, 0, stream>>>(W0, B0T);
    castB<<<NP, KP2, 0, stream>>>(W, BT);
    prep_kernel<<<(NN + 3) / 4, 256, 0, stream>>>(x, edge_attr, rowptr, csr, A1);

    // gemm1: 256 blocks (1/CU), 512 thr (8 waves, 2/SIMD), full N=320 panel
    gemm_stream<0, KP1, 320, 2, 4, 196, 512><<<dim3(256, 1), 512, 0, stream>>>(
        A1, B0T, b0, nullptr, h0, h0b, NN);
    agg_kernel<<<(NN + 3) / 4, 256, 0, stream>>>(h0b, rowptr, csr, aggB);
    // gemm2: r6-exact (128,2) blocks, 256 thr, N-half=160 panel
    gemm_stream<1, KP2, 160, 2, 2, 391, 256><<<dim3(128, 2), 256, 0, stream>>>(
        aggB, BT, b, h0, h, nullptr, NN);
}